// Round 1
// 644.378 us; speedup vs baseline: 1.2703x; 1.2703x over previous
//
#include <hip/hip_runtime.h>
#include <hip/hip_bf16.h>

#define N_TOK 32768
#define D_IN 1024
#define D_OUT 1024
#define NE 8

#define BM 128
#define BN 128
#define BK 64
#define PAD 72  // halfword pitch: 144 B rows -> 16B aligned, ~2-way LDS conflicts (free)

#define GBLK 64        // tokens per gate block (64 rows, 4 lanes per token)
#define GCH 64         // dims per staged chunk
#define NCH (D_IN / GCH)
#define CNT_STRIDE 64  // ints; pads each routing counter to its own 256B cache line

typedef __attribute__((ext_vector_type(8))) short short8;
typedef __attribute__((ext_vector_type(4))) float floatx4;

__device__ __forceinline__ unsigned short f2bf(float f) {
    union { float f; unsigned u; } v; v.f = f;
    unsigned r = v.u + 0x7fffu + ((v.u >> 16) & 1u);  // RNE
    return (unsigned short)(r >> 16);
}
__device__ __forceinline__ float bf2f(unsigned short u) {
    union { unsigned u; float f; } v; v.u = ((unsigned)u) << 16;
    return v.f;
}

// ---------------- zero the padded routing counters ----------------------------
__global__ void zero_cnt(int* __restrict__ cnt) {
    int i = blockIdx.x * 256 + threadIdx.x;
    if (i < 16 * CNT_STRIDE) cnt[i] = 0;
}

// ---------------- We [e][i][o] fp32 -> WeT [e][o][i] bf16 ---------------------
__global__ __launch_bounds__(256) void transpose_we(
    const float* __restrict__ We, unsigned short* __restrict__ WeT)
{
    __shared__ unsigned short tile[64 * 65];
    int e = blockIdx.z;
    int i0 = blockIdx.x * 64, o0 = blockIdx.y * 64;
    const float* src = We + ((size_t)e * D_IN + i0) * D_OUT + o0;
#pragma unroll
    for (int it = 0; it < 16; ++it) {
        int idx = threadIdx.x + it * 256;      // 0..4095
        int r = idx >> 6, c = idx & 63;
        tile[r * 65 + c] = f2bf(src[(size_t)r * D_OUT + c]);
    }
    __syncthreads();
    unsigned short* dst = WeT + ((size_t)e * D_OUT + o0) * D_IN + i0;
#pragma unroll
    for (int it = 0; it < 16; ++it) {
        int idx = threadIdx.x + it * 256;
        int r = idx >> 6, c = idx & 63;
        dst[(size_t)r * D_IN + c] = tile[c * 65 + r];
    }
}

// ---------------- gating v2: 4 lanes/token, chunked LDS staging ---------------
// Each block: 256 threads, 64 tokens. Lane (t,q) accumulates fp64 partial
// logits for token row=wave*16+t over dim-quarter q (16 dims per 64-dim chunk).
// x is staged coalesced through LDS (fused bf16 conversion -> xb). Wg chunk is
// staged q-padded ([4][136]) so the 8-float rows read as 2x ds_read_b128,
// conflict-free across q, broadcast across the 16 t-lanes.
// Reduce = 2 shfl_xor stages (q bits). Top-k/softmax computed redundantly by
// all 4 q-lanes (no divergence); q==0 writes results + LDS histogram.
__global__ __launch_bounds__(256) void gate_kernel(
    const float* __restrict__ x, const float* __restrict__ Wg,
    const float* __restrict__ bg,
    int* __restrict__ top_i, float* __restrict__ gates,
    int* __restrict__ cnt, int* __restrict__ lists,
    unsigned short* __restrict__ xb)
{
    __shared__ float xs[GBLK][GCH + 1];   // pitch 65: compute reads 2-way (free)
    __shared__ float wgs[4][136];         // q-pitch 136: b128 starts 8 banks apart
    __shared__ int lcnt[16];
    __shared__ int lbase[16];
    __shared__ int ltoks[16][GBLK];

    int tid = threadIdx.x;
    if (tid < 16) lcnt[tid] = 0;

    int tok0 = blockIdx.x * GBLK;
    int lane = tid & 63, wave = tid >> 6;
    int t = lane >> 2, q = lane & 3;
    int row = wave * 16 + t;              // block-local token owned by this lane
    int token = tok0 + row;

    double acc[NE] = {};

#pragma unroll 1
    for (int c = 0; c < NCH; ++c) {
        int cb = c * GCH;
        __syncthreads();                  // previous chunk fully consumed
        // stage Wg chunk (512 floats, 2 per thread), coalesced read
        {
            int i = tid;
#pragma unroll
            for (int it = 0; it < 2; ++it, i += 256) {
                float v = Wg[(size_t)cb * NE + i];
                int d = i >> 3, e = i & 7;            // d in [0,64)
                wgs[d >> 4][(d & 15) * 8 + e] = v;
            }
        }
        // stage x chunk: 64 tok x 64 dims, fused bf16 convert -> xb
#pragma unroll
        for (int it = 0; it < 4; ++it) {
            int idx = tid + it * 256;                 // 0..1023 float4 slots
            int r = idx >> 4, c4 = (idx & 15) * 4;
            const float4 v = *(const float4*)(x + (size_t)(tok0 + r) * D_IN + cb + c4);
            xs[r][c4 + 0] = v.x; xs[r][c4 + 1] = v.y;
            xs[r][c4 + 2] = v.z; xs[r][c4 + 3] = v.w;
            ushort4 pk;
            pk.x = f2bf(v.x); pk.y = f2bf(v.y); pk.z = f2bf(v.z); pk.w = f2bf(v.w);
            *(ushort4*)(xb + (size_t)(tok0 + r) * D_IN + cb + c4) = pk;
        }
        __syncthreads();
        // accumulate this lane's dim-quarter: dims cb + q*16 + jj
#pragma unroll
        for (int jj = 0; jj < 16; ++jj) {
            double xd = (double)xs[row][q * 16 + jj];
            const float* wr = &wgs[q][jj * 8];
#pragma unroll
            for (int e = 0; e < NE; ++e)
                acc[e] += xd * (double)wr[e];
        }
    }

    // reduce across the 4 q-lanes (lane bits 0,1)
#pragma unroll
    for (int off = 1; off <= 2; off <<= 1)
#pragma unroll
        for (int e = 0; e < NE; ++e)
            acc[e] += __shfl_xor(acc[e], off, 64);

    // logits + top-2 + softmax, computed by all lanes (no divergence)
    float lg[NE];
#pragma unroll
    for (int e = 0; e < NE; ++e) lg[e] = tanhf((float)(acc[e] + (double)bg[e]));
    int i0 = 0;
    for (int e = 1; e < NE; ++e) if (lg[e] > lg[i0]) i0 = e;   // lowest idx wins ties
    int i1 = (i0 == 0) ? 1 : 0;
    for (int e = 0; e < NE; ++e) { if (e == i0) continue; if (lg[e] > lg[i1]) i1 = e; }
    float tt = expf(lg[i1] - lg[i0]);
    float g0 = 1.0f / (1.0f + tt);
    float g1 = tt * g0;

    if (q == 0) {
        top_i[token * 2 + 0] = i0; top_i[token * 2 + 1] = i1;
        gates[token * 2 + 0] = g0; gates[token * 2 + 1] = g1;
        int p0 = atomicAdd(&lcnt[i0], 1);          // LDS atomic: cheap
        ltoks[i0][p0] = token;
        int p1 = atomicAdd(&lcnt[NE + i1], 1);
        ltoks[NE + i1][p1] = token;
    }
    __syncthreads();
    if (tid < 16) lbase[tid] = atomicAdd(&cnt[tid * CNT_STRIDE], lcnt[tid]);
    __syncthreads();
    int g = tid >> 4, j = tid & 15;                // 16 threads per list
    int n = lcnt[g];
    int* dst = lists + (size_t)g * N_TOK + lbase[g];
    for (int k = j; k < n; k += 16) dst[k] = ltoks[g][k];
}

// ---------------- gathered-token bf16 MFMA GEMM: h = x[toks] @ We[e] + be -----
// grid: (ntile=8, mtile<=256, expert=8); block 256 (4 waves, 2x2, 64x64 each)
template <bool USEBF>
__global__ __launch_bounds__(256) void gemm_slot(
    const float* __restrict__ x, const unsigned short* __restrict__ xb,
    const unsigned short* __restrict__ WeT,
    const float* __restrict__ be, const int* __restrict__ lists,
    const int* __restrict__ cnt, int slot, unsigned short* __restrict__ h)
{
    int e = blockIdx.z;
    int count = cnt[(slot * NE + e) * CNT_STRIDE];
    int m0 = blockIdx.y * BM;
    if (m0 >= count) return;
    int n0 = blockIdx.x * BN;
    const int* list = lists + (size_t)(slot * NE + e) * N_TOK;

    __shared__ int toks[BM];
    __shared__ unsigned short As[BM * PAD];
    __shared__ unsigned short Bs[BN * PAD];

    int tid = threadIdx.x;
    if (tid < BM) {
        int r = m0 + tid; if (r > count - 1) r = count - 1;  // tail duplicates last row
        toks[tid] = list[r];
    }
    __syncthreads();

    int lane = tid & 63, wave = tid >> 6;
    int wm = (wave & 1) * 64, wn = (wave >> 1) * 64;
    int q = lane & 15, quad = lane >> 4;

    floatx4 acc[4][4] = {};

    const unsigned short* Bglob = WeT + ((size_t)e * D_OUT + n0) * D_IN;

    for (int kb = 0; kb < D_IN; kb += BK) {
        if (USEBF) {
#pragma unroll
            for (int it = 0; it < 4; ++it) {
                int idx = tid + it * 256;      // 0..1023 uint4s
                int m = idx >> 3, kq = idx & 7;
                *(uint4*)&As[m * PAD + kq * 8] =
                    *(const uint4*)(xb + (size_t)toks[m] * D_IN + kb + kq * 8);
            }
        } else {
#pragma unroll
            for (int it = 0; it < 8; ++it) {
                int idx = tid + it * 256;      // 0..2047 float4s
                int m = idx >> 4, kq = idx & 15;
                float4 v = *(const float4*)(x + (size_t)toks[m] * D_IN + kb + kq * 4);
                ushort4 pk;
                pk.x = f2bf(v.x); pk.y = f2bf(v.y); pk.z = f2bf(v.z); pk.w = f2bf(v.w);
                *(ushort4*)&As[m * PAD + kq * 4] = pk;
            }
        }
#pragma unroll
        for (int it = 0; it < 4; ++it) {
            int idx = tid + it * 256;          // 0..1023 uint4s
            int n = idx >> 3, kq = idx & 7;
            *(uint4*)&Bs[n * PAD + kq * 8] =
                *(const uint4*)(Bglob + (size_t)n * D_IN + kb + kq * 8);
        }
        __syncthreads();

#pragma unroll
        for (int ks = 0; ks < BK; ks += 32) {
            short8 af[4], bfr[4];
#pragma unroll
            for (int i = 0; i < 4; ++i)
                af[i] = *(const short8*)&As[(wm + i * 16 + q) * PAD + ks + quad * 8];
#pragma unroll
            for (int j = 0; j < 4; ++j)
                bfr[j] = *(const short8*)&Bs[(wn + j * 16 + q) * PAD + ks + quad * 8];
#pragma unroll
            for (int i = 0; i < 4; ++i)
#pragma unroll
                for (int j = 0; j < 4; ++j)
                    acc[i][j] = __builtin_amdgcn_mfma_f32_16x16x32_bf16(
                        af[i], bfr[j], acc[i][j], 0, 0, 0);
        }
        __syncthreads();
    }

#pragma unroll
    for (int i = 0; i < 4; ++i) {
#pragma unroll
        for (int r = 0; r < 4; ++r) {
            int m = wm + i * 16 + quad * 4 + r;
            if (m0 + m < count) {
                int tok = toks[m];
#pragma unroll
                for (int j = 0; j < 4; ++j) {
                    int n = n0 + wn + j * 16 + q;
                    float v = acc[i][j][r] + be[(size_t)e * D_OUT + n];
                    h[(size_t)tok * D_OUT + n] = f2bf(v);
                }
            }
        }
    }
}

// ---------------- GELU(exact) + LayerNorm + gamma/beta + gated combine --------
__global__ __launch_bounds__(256) void ln_combine(
    const unsigned short* __restrict__ h, const float* __restrict__ gamma,
    const float* __restrict__ beta, const float* __restrict__ gates,
    const int* __restrict__ top_i, int slot, float* __restrict__ out)
{
    int wave = threadIdx.x >> 6, lane = threadIdx.x & 63;
    int token = blockIdx.x * 4 + wave;
    int e = top_i[token * 2 + slot];
    float gate = gates[token * 2 + slot];
    const unsigned short* hr = h + (size_t)token * D_OUT;

    float g[16], sum = 0.f, sumsq = 0.f;
#pragma unroll
    for (int jj = 0; jj < 4; ++jj) {
        int n = jj * 256 + lane * 4;
        uint2 pk = *(const uint2*)(hr + n);    // 4 bf16
        float v0 = bf2f((unsigned short)(pk.x & 0xffff));
        float v1 = bf2f((unsigned short)(pk.x >> 16));
        float v2 = bf2f((unsigned short)(pk.y & 0xffff));
        float v3 = bf2f((unsigned short)(pk.y >> 16));
        float g0 = 0.5f * v0 * (1.0f + erff(v0 * 0.70710678118654752f));
        float g1 = 0.5f * v1 * (1.0f + erff(v1 * 0.70710678118654752f));
        float g2 = 0.5f * v2 * (1.0f + erff(v2 * 0.70710678118654752f));
        float g3 = 0.5f * v3 * (1.0f + erff(v3 * 0.70710678118654752f));
        g[jj * 4 + 0] = g0; g[jj * 4 + 1] = g1; g[jj * 4 + 2] = g2; g[jj * 4 + 3] = g3;
        sum   += g0 + g1 + g2 + g3;
        sumsq += g0 * g0 + g1 * g1 + g2 * g2 + g3 * g3;
    }
#pragma unroll
    for (int off = 32; off; off >>= 1) {
        sum   += __shfl_xor(sum, off, 64);
        sumsq += __shfl_xor(sumsq, off, 64);
    }
    float mu  = sum * (1.0f / 1024.0f);
    float var = sumsq * (1.0f / 1024.0f) - mu * mu;
    float rs  = rsqrtf(var + 1e-5f);

    const float* gm = gamma + (size_t)e * D_OUT;
    const float* bt = beta  + (size_t)e * D_OUT;
    float* orow = out + (size_t)token * D_OUT;
#pragma unroll
    for (int jj = 0; jj < 4; ++jj) {
        int n = jj * 256 + lane * 4;
        float4 gm4 = *(const float4*)(gm + n);
        float4 bt4 = *(const float4*)(bt + n);
        float4 o;
        o.x = gate * ((g[jj * 4 + 0] - mu) * rs * gm4.x + bt4.x);
        o.y = gate * ((g[jj * 4 + 1] - mu) * rs * gm4.y + bt4.y);
        o.z = gate * ((g[jj * 4 + 2] - mu) * rs * gm4.z + bt4.z);
        o.w = gate * ((g[jj * 4 + 3] - mu) * rs * gm4.w + bt4.w);
        if (slot == 0) {
            *(float4*)(orow + n) = o;
        } else {
            float4 p = *(const float4*)(orow + n);
            p.x += o.x; p.y += o.y; p.z += o.z; p.w += o.w;
            *(float4*)(orow + n) = p;
        }
    }
}

extern "C" void kernel_launch(void* const* d_in, const int* in_sizes, int n_in,
                              void* d_out, int out_size, void* d_ws, size_t ws_size,
                              hipStream_t stream) {
    const float* x     = (const float*)d_in[0];
    const float* Wg    = (const float*)d_in[1];
    const float* bg    = (const float*)d_in[2];
    const float* We    = (const float*)d_in[3];
    const float* be    = (const float*)d_in[4];
    const float* gamma = (const float*)d_in[5];
    const float* beta  = (const float*)d_in[6];
    float* out = (float*)d_out;

    char* w = (char*)d_ws;
    size_t off = 0;
    int*   cnt   = (int*)(w + off);            off += (size_t)16 * CNT_STRIDE * 4;
    int*   top_i = (int*)(w + off);            off += (size_t)N_TOK * 2 * 4;
    float* gates = (float*)(w + off);          off += (size_t)N_TOK * 2 * 4;
    int*   lists = (int*)(w + off);            off += (size_t)16 * N_TOK * 4;
    unsigned short* WeT = (unsigned short*)(w + off); off += (size_t)NE * D_IN * D_OUT * 2;
    unsigned short* h   = (unsigned short*)(w + off); off += (size_t)N_TOK * D_OUT * 2;
    size_t xb_bytes = (size_t)N_TOK * D_IN * 2;
    bool use_bf = (off + xb_bytes) <= ws_size;
    unsigned short* xb = use_bf ? (unsigned short*)(w + off) : h;
    if (use_bf) off += xb_bytes;

    zero_cnt<<<(16 * CNT_STRIDE + 255) / 256, 256, 0, stream>>>(cnt);
    transpose_we<<<dim3(16, 16, NE), 256, 0, stream>>>(We, WeT);
    gate_kernel<<<N_TOK / GBLK, 256, 0, stream>>>(x, Wg, bg, top_i, gates, cnt, lists, xb);
    for (int s = 0; s < 2; ++s) {
        if (use_bf)
            gemm_slot<true><<<dim3(D_OUT / BN, N_TOK / BM, NE), 256, 0, stream>>>(
                x, xb, WeT, be, lists, cnt, s, h);
        else
            gemm_slot<false><<<dim3(D_OUT / BN, N_TOK / BM, NE), 256, 0, stream>>>(
                x, xb, WeT, be, lists, cnt, s, h);
        ln_combine<<<N_TOK / 4, 256, 0, stream>>>(h, gamma, beta, gates, top_i, s, out);
    }
}

// Round 2
// 582.992 us; speedup vs baseline: 1.4041x; 1.1053x over previous
//
#include <hip/hip_runtime.h>
#include <hip/hip_bf16.h>

#define N_TOK 32768
#define D_IN 1024
#define D_OUT 1024
#define NE 8

#define BM 128
#define BN 128
#define BK 64
#define PAD 72  // (legacy fallback path only)

#define GBLK 64        // tokens per gate block (64 rows, 4 lanes per token)
#define GCH 64         // dims per staged chunk
#define NCH (D_IN / GCH)
#define CNT_STRIDE 64  // ints; pads each routing counter to its own 256B cache line

#define AS1 __attribute__((address_space(1)))
#define AS3 __attribute__((address_space(3)))

typedef __attribute__((ext_vector_type(8))) short short8;
typedef __attribute__((ext_vector_type(4))) float floatx4;

__device__ __forceinline__ unsigned short f2bf(float f) {
    union { float f; unsigned u; } v; v.f = f;
    unsigned r = v.u + 0x7fffu + ((v.u >> 16) & 1u);  // RNE
    return (unsigned short)(r >> 16);
}
__device__ __forceinline__ float bf2f(unsigned short u) {
    union { unsigned u; float f; } v; v.u = ((unsigned)u) << 16;
    return v.f;
}

// async 16B global->LDS (direct, no VGPR round trip). Global addr is per-lane;
// LDS dest must be wave-uniform base (+ lane*16 implicit).
__device__ __forceinline__ void gl_lds16(const void* g, void* l) {
    __builtin_amdgcn_global_load_lds((const AS1 unsigned int*)g,
                                     (AS3 unsigned int*)l, 16, 0, 0);
}

// ---------------- zero the padded routing counters ----------------------------
__global__ void zero_cnt(int* __restrict__ cnt) {
    int i = blockIdx.x * 256 + threadIdx.x;
    if (i < 16 * CNT_STRIDE) cnt[i] = 0;
}

// ---------------- We [e][i][o] fp32 -> WeT [e][o][i] bf16 ---------------------
__global__ __launch_bounds__(256) void transpose_we(
    const float* __restrict__ We, unsigned short* __restrict__ WeT)
{
    __shared__ unsigned short tile[64 * 65];
    int e = blockIdx.z;
    int i0 = blockIdx.x * 64, o0 = blockIdx.y * 64;
    const float* src = We + ((size_t)e * D_IN + i0) * D_OUT + o0;
#pragma unroll
    for (int it = 0; it < 16; ++it) {
        int idx = threadIdx.x + it * 256;      // 0..4095
        int r = idx >> 6, c = idx & 63;
        tile[r * 65 + c] = f2bf(src[(size_t)r * D_OUT + c]);
    }
    __syncthreads();
    unsigned short* dst = WeT + ((size_t)e * D_OUT + o0) * D_IN + i0;
#pragma unroll
    for (int it = 0; it < 16; ++it) {
        int idx = threadIdx.x + it * 256;
        int r = idx >> 6, c = idx & 63;
        dst[(size_t)r * D_IN + c] = tile[c * 65 + r];
    }
}

// ---------------- gating v2: 4 lanes/token, chunked LDS staging ---------------
__global__ __launch_bounds__(256) void gate_kernel(
    const float* __restrict__ x, const float* __restrict__ Wg,
    const float* __restrict__ bg,
    int* __restrict__ top_i, float* __restrict__ gates,
    int* __restrict__ cnt, int* __restrict__ lists,
    unsigned short* __restrict__ xb)
{
    __shared__ float xs[GBLK][GCH + 1];   // pitch 65: compute reads 2-way (free)
    __shared__ float wgs[4][136];         // q-pitch 136: b128 starts 8 banks apart
    __shared__ int lcnt[16];
    __shared__ int lbase[16];
    __shared__ int ltoks[16][GBLK];

    int tid = threadIdx.x;
    if (tid < 16) lcnt[tid] = 0;

    int tok0 = blockIdx.x * GBLK;
    int lane = tid & 63, wave = tid >> 6;
    int t = lane >> 2, q = lane & 3;
    int row = wave * 16 + t;              // block-local token owned by this lane
    int token = tok0 + row;

    double acc[NE] = {};

#pragma unroll 1
    for (int c = 0; c < NCH; ++c) {
        int cb = c * GCH;
        __syncthreads();                  // previous chunk fully consumed
        {
            int i = tid;
#pragma unroll
            for (int it = 0; it < 2; ++it, i += 256) {
                float v = Wg[(size_t)cb * NE + i];
                int d = i >> 3, e = i & 7;            // d in [0,64)
                wgs[d >> 4][(d & 15) * 8 + e] = v;
            }
        }
#pragma unroll
        for (int it = 0; it < 4; ++it) {
            int idx = tid + it * 256;                 // 0..1023 float4 slots
            int r = idx >> 4, c4 = (idx & 15) * 4;
            const float4 v = *(const float4*)(x + (size_t)(tok0 + r) * D_IN + cb + c4);
            xs[r][c4 + 0] = v.x; xs[r][c4 + 1] = v.y;
            xs[r][c4 + 2] = v.z; xs[r][c4 + 3] = v.w;
            ushort4 pk;
            pk.x = f2bf(v.x); pk.y = f2bf(v.y); pk.z = f2bf(v.z); pk.w = f2bf(v.w);
            *(ushort4*)(xb + (size_t)(tok0 + r) * D_IN + cb + c4) = pk;
        }
        __syncthreads();
#pragma unroll
        for (int jj = 0; jj < 16; ++jj) {
            double xd = (double)xs[row][q * 16 + jj];
            const float* wr = &wgs[q][jj * 8];
#pragma unroll
            for (int e = 0; e < NE; ++e)
                acc[e] += xd * (double)wr[e];
        }
    }

#pragma unroll
    for (int off = 1; off <= 2; off <<= 1)
#pragma unroll
        for (int e = 0; e < NE; ++e)
            acc[e] += __shfl_xor(acc[e], off, 64);

    float lg[NE];
#pragma unroll
    for (int e = 0; e < NE; ++e) lg[e] = tanhf((float)(acc[e] + (double)bg[e]));
    int i0 = 0;
    for (int e = 1; e < NE; ++e) if (lg[e] > lg[i0]) i0 = e;   // lowest idx wins ties
    int i1 = (i0 == 0) ? 1 : 0;
    for (int e = 0; e < NE; ++e) { if (e == i0) continue; if (lg[e] > lg[i1]) i1 = e; }
    float tt = expf(lg[i1] - lg[i0]);
    float g0 = 1.0f / (1.0f + tt);
    float g1 = tt * g0;

    if (q == 0) {
        top_i[token * 2 + 0] = i0; top_i[token * 2 + 1] = i1;
        gates[token * 2 + 0] = g0; gates[token * 2 + 1] = g1;
        int p0 = atomicAdd(&lcnt[i0], 1);
        ltoks[i0][p0] = token;
        int p1 = atomicAdd(&lcnt[NE + i1], 1);
        ltoks[NE + i1][p1] = token;
    }
    __syncthreads();
    if (tid < 16) lbase[tid] = atomicAdd(&cnt[tid * CNT_STRIDE], lcnt[tid]);
    __syncthreads();
    int g = tid >> 4, j = tid & 15;
    int n = lcnt[g];
    int* dst = lists + (size_t)g * N_TOK + lbase[g];
    for (int k = j; k < n; k += 16) dst[k] = ltoks[g][k];
}

// ---------------- gathered-token bf16 MFMA GEMM v2 ----------------------------
// global_load_lds(16B) direct staging, linear LDS [row][64] halfwords with
// both-sides XOR chunk swizzle (c ^= row&7): conflict-free ds_read_b128, no
// ds_writes, no repack VALU. grid: (ntile=8, mtile, z = slot*8+e).
__global__ __launch_bounds__(256) void gemm_slot2(
    const unsigned short* __restrict__ xb,
    const unsigned short* __restrict__ WeT,
    const float* __restrict__ be, const int* __restrict__ lists,
    const int* __restrict__ cnt, int zoff,
    unsigned short* __restrict__ h0, unsigned short* __restrict__ h1)
{
    int z = blockIdx.z + zoff;
    int slot = z >> 3, e = z & 7;
    unsigned short* __restrict__ h = slot ? h1 : h0;
    int count = cnt[z * CNT_STRIDE];
    int m0 = blockIdx.y * BM;
    if (m0 >= count) return;
    int n0 = blockIdx.x * BN;
    const int* list = lists + (size_t)z * N_TOK;

    __shared__ int toks[BM];
    __shared__ __align__(16) unsigned short As[BM * BK];   // 16 KB, linear+swizzled
    __shared__ __align__(16) unsigned short Bs[BN * BK];   // 16 KB

    int tid = threadIdx.x;
    if (tid < BM) {
        int r = m0 + tid; if (r > count - 1) r = count - 1;  // tail duplicates last row
        toks[tid] = list[r];
    }
    __syncthreads();

    int lane = tid & 63, wave = tid >> 6;
    int wm = (wave & 1) * 64, wn = (wave >> 1) * 64;
    int q = lane & 15, quad = lane >> 4;

    const unsigned short* Bglob = WeT + ((size_t)e * D_OUT + n0) * D_IN;

    // Precompute per-thread staging addresses (source pre-swizzled chunk).
    const unsigned short* asrc[4];
    const unsigned short* bsrc[4];
    unsigned short* adst[4];
    unsigned short* bdst[4];
#pragma unroll
    for (int it = 0; it < 4; ++it) {
        int idx = tid + it * 256;            // 0..1023 16B-chunks
        int m = idx >> 3, c = idx & 7;
        int sc = c ^ (m & 7);                // inverse(=same) of read-side XOR
        asrc[it] = xb + (size_t)toks[m] * D_IN + sc * 8;
        bsrc[it] = Bglob + (size_t)m * D_IN + sc * 8;
        unsigned short* base = (unsigned short*)0;
        adst[it] = As + (size_t)(it * 256 + (tid & 192)) * 8;  // wave-uniform
        bdst[it] = Bs + (size_t)(it * 256 + (tid & 192)) * 8;
        (void)base;
    }

    floatx4 acc[4][4] = {};

    for (int kb = 0; kb < D_IN; kb += BK) {
#pragma unroll
        for (int it = 0; it < 4; ++it)
            gl_lds16(asrc[it] + kb, adst[it]);
#pragma unroll
        for (int it = 0; it < 4; ++it)
            gl_lds16(bsrc[it] + kb, bdst[it]);
        __syncthreads();                      // drains vmcnt before use

#pragma unroll
        for (int ks = 0; ks < BK; ks += 32) {
            int cb = ks >> 3;                 // chunk base: 0 or 4
            short8 af[4], bfr[4];
#pragma unroll
            for (int i = 0; i < 4; ++i) {
                int row = wm + i * 16 + q;
                int ch = (cb + quad) ^ (row & 7);
                af[i] = *(const short8*)&As[row * BK + ch * 8];
            }
#pragma unroll
            for (int j = 0; j < 4; ++j) {
                int row = wn + j * 16 + q;
                int ch = (cb + quad) ^ (row & 7);
                bfr[j] = *(const short8*)&Bs[row * BK + ch * 8];
            }
#pragma unroll
            for (int i = 0; i < 4; ++i)
#pragma unroll
                for (int j = 0; j < 4; ++j)
                    acc[i][j] = __builtin_amdgcn_mfma_f32_16x16x32_bf16(
                        af[i], bfr[j], acc[i][j], 0, 0, 0);
        }
        __syncthreads();
    }

#pragma unroll
    for (int i = 0; i < 4; ++i) {
#pragma unroll
        for (int r = 0; r < 4; ++r) {
            int m = wm + i * 16 + quad * 4 + r;
            if (m0 + m < count) {
                int tok = toks[m];
#pragma unroll
                for (int j = 0; j < 4; ++j) {
                    int n = n0 + wn + j * 16 + q;
                    float v = acc[i][j][r] + be[(size_t)e * D_OUT + n];
                    h[(size_t)tok * D_OUT + n] = f2bf(v);
                }
            }
        }
    }
}

// ---------------- legacy reg-staged GEMM (fallback when xb doesn't fit) ------
__global__ __launch_bounds__(256) void gemm_slot_f32(
    const float* __restrict__ x,
    const unsigned short* __restrict__ WeT,
    const float* __restrict__ be, const int* __restrict__ lists,
    const int* __restrict__ cnt, int slot, unsigned short* __restrict__ h)
{
    int e = blockIdx.z;
    int count = cnt[(slot * NE + e) * CNT_STRIDE];
    int m0 = blockIdx.y * BM;
    if (m0 >= count) return;
    int n0 = blockIdx.x * BN;
    const int* list = lists + (size_t)(slot * NE + e) * N_TOK;

    __shared__ int toks[BM];
    __shared__ unsigned short As[BM * PAD];
    __shared__ unsigned short Bs[BN * PAD];

    int tid = threadIdx.x;
    if (tid < BM) {
        int r = m0 + tid; if (r > count - 1) r = count - 1;
        toks[tid] = list[r];
    }
    __syncthreads();

    int lane = tid & 63, wave = tid >> 6;
    int wm = (wave & 1) * 64, wn = (wave >> 1) * 64;
    int q = lane & 15, quad = lane >> 4;

    floatx4 acc[4][4] = {};
    const unsigned short* Bglob = WeT + ((size_t)e * D_OUT + n0) * D_IN;

    for (int kb = 0; kb < D_IN; kb += BK) {
#pragma unroll
        for (int it = 0; it < 8; ++it) {
            int idx = tid + it * 256;
            int m = idx >> 4, kq = idx & 15;
            float4 v = *(const float4*)(x + (size_t)toks[m] * D_IN + kb + kq * 4);
            ushort4 pk;
            pk.x = f2bf(v.x); pk.y = f2bf(v.y); pk.z = f2bf(v.z); pk.w = f2bf(v.w);
            *(ushort4*)&As[m * PAD + kq * 4] = pk;
        }
#pragma unroll
        for (int it = 0; it < 4; ++it) {
            int idx = tid + it * 256;
            int n = idx >> 3, kq = idx & 7;
            *(uint4*)&Bs[n * PAD + kq * 8] =
                *(const uint4*)(Bglob + (size_t)n * D_IN + kb + kq * 8);
        }
        __syncthreads();
#pragma unroll
        for (int ks = 0; ks < BK; ks += 32) {
            short8 af[4], bfr[4];
#pragma unroll
            for (int i = 0; i < 4; ++i)
                af[i] = *(const short8*)&As[(wm + i * 16 + q) * PAD + ks + quad * 8];
#pragma unroll
            for (int j = 0; j < 4; ++j)
                bfr[j] = *(const short8*)&Bs[(wn + j * 16 + q) * PAD + ks + quad * 8];
#pragma unroll
            for (int i = 0; i < 4; ++i)
#pragma unroll
                for (int j = 0; j < 4; ++j)
                    acc[i][j] = __builtin_amdgcn_mfma_f32_16x16x32_bf16(
                        af[i], bfr[j], acc[i][j], 0, 0, 0);
        }
        __syncthreads();
    }

#pragma unroll
    for (int i = 0; i < 4; ++i) {
#pragma unroll
        for (int r = 0; r < 4; ++r) {
            int m = wm + i * 16 + quad * 4 + r;
            if (m0 + m < count) {
                int tok = toks[m];
#pragma unroll
                for (int j = 0; j < 4; ++j) {
                    int n = n0 + wn + j * 16 + q;
                    float v = acc[i][j][r] + be[(size_t)e * D_OUT + n];
                    h[(size_t)tok * D_OUT + n] = f2bf(v);
                }
            }
        }
    }
}

// ---------------- GELU(exact) + LN + affine, one slot (fallback) --------------
__global__ __launch_bounds__(256) void ln_combine(
    const unsigned short* __restrict__ h, const float* __restrict__ gamma,
    const float* __restrict__ beta, const float* __restrict__ gates,
    const int* __restrict__ top_i, int slot, float* __restrict__ out)
{
    int wave = threadIdx.x >> 6, lane = threadIdx.x & 63;
    int token = blockIdx.x * 4 + wave;
    int e = top_i[token * 2 + slot];
    float gate = gates[token * 2 + slot];
    const unsigned short* hr = h + (size_t)token * D_OUT;

    float g[16], sum = 0.f, sumsq = 0.f;
#pragma unroll
    for (int jj = 0; jj < 4; ++jj) {
        int n = jj * 256 + lane * 4;
        uint2 pk = *(const uint2*)(hr + n);
        float v0 = bf2f((unsigned short)(pk.x & 0xffff));
        float v1 = bf2f((unsigned short)(pk.x >> 16));
        float v2 = bf2f((unsigned short)(pk.y & 0xffff));
        float v3 = bf2f((unsigned short)(pk.y >> 16));
        float g0 = 0.5f * v0 * (1.0f + erff(v0 * 0.70710678118654752f));
        float g1 = 0.5f * v1 * (1.0f + erff(v1 * 0.70710678118654752f));
        float g2 = 0.5f * v2 * (1.0f + erff(v2 * 0.70710678118654752f));
        float g3 = 0.5f * v3 * (1.0f + erff(v3 * 0.70710678118654752f));
        g[jj * 4 + 0] = g0; g[jj * 4 + 1] = g1; g[jj * 4 + 2] = g2; g[jj * 4 + 3] = g3;
        sum   += g0 + g1 + g2 + g3;
        sumsq += g0 * g0 + g1 * g1 + g2 * g2 + g3 * g3;
    }
#pragma unroll
    for (int off = 32; off; off >>= 1) {
        sum   += __shfl_xor(sum, off, 64);
        sumsq += __shfl_xor(sumsq, off, 64);
    }
    float mu  = sum * (1.0f / 1024.0f);
    float var = sumsq * (1.0f / 1024.0f) - mu * mu;
    float rs  = rsqrtf(var + 1e-5f);

    const float* gm = gamma + (size_t)e * D_OUT;
    const float* bt = beta  + (size_t)e * D_OUT;
    float* orow = out + (size_t)token * D_OUT;
#pragma unroll
    for (int jj = 0; jj < 4; ++jj) {
        int n = jj * 256 + lane * 4;
        float4 gm4 = *(const float4*)(gm + n);
        float4 bt4 = *(const float4*)(bt + n);
        float4 o;
        o.x = gate * ((g[jj * 4 + 0] - mu) * rs * gm4.x + bt4.x);
        o.y = gate * ((g[jj * 4 + 1] - mu) * rs * gm4.y + bt4.y);
        o.z = gate * ((g[jj * 4 + 2] - mu) * rs * gm4.z + bt4.z);
        o.w = gate * ((g[jj * 4 + 3] - mu) * rs * gm4.w + bt4.w);
        if (slot == 0) {
            *(float4*)(orow + n) = o;
        } else {
            float4 p = *(const float4*)(orow + n);
            p.x += o.x; p.y += o.y; p.z += o.z; p.w += o.w;
            *(float4*)(orow + n) = p;
        }
    }
}

// ---------------- fused both-slot GELU + LN + gated combine -------------------
// Reads h0 and h1, writes out exactly once: 268 MB traffic vs 536 MB split.
__global__ __launch_bounds__(256) void ln_combine2(
    const unsigned short* __restrict__ h0, const unsigned short* __restrict__ h1,
    const float* __restrict__ gamma, const float* __restrict__ beta,
    const float* __restrict__ gates, const int* __restrict__ top_i,
    float* __restrict__ out)
{
    int wave = threadIdx.x >> 6, lane = threadIdx.x & 63;
    int token = blockIdx.x * 4 + wave;
    int e0 = top_i[token * 2 + 0], e1 = top_i[token * 2 + 1];
    float gate0 = gates[token * 2 + 0], gate1 = gates[token * 2 + 1];

    float g[2][16], mu[2], rs[2];
    const unsigned short* hr[2] = { h0 + (size_t)token * D_OUT,
                                    h1 + (size_t)token * D_OUT };
#pragma unroll
    for (int s = 0; s < 2; ++s) {
        float sum = 0.f, sumsq = 0.f;
#pragma unroll
        for (int jj = 0; jj < 4; ++jj) {
            int n = jj * 256 + lane * 4;
            uint2 pk = *(const uint2*)(hr[s] + n);
            float v0 = bf2f((unsigned short)(pk.x & 0xffff));
            float v1 = bf2f((unsigned short)(pk.x >> 16));
            float v2 = bf2f((unsigned short)(pk.y & 0xffff));
            float v3 = bf2f((unsigned short)(pk.y >> 16));
            float a0 = 0.5f * v0 * (1.0f + erff(v0 * 0.70710678118654752f));
            float a1 = 0.5f * v1 * (1.0f + erff(v1 * 0.70710678118654752f));
            float a2 = 0.5f * v2 * (1.0f + erff(v2 * 0.70710678118654752f));
            float a3 = 0.5f * v3 * (1.0f + erff(v3 * 0.70710678118654752f));
            g[s][jj * 4 + 0] = a0; g[s][jj * 4 + 1] = a1;
            g[s][jj * 4 + 2] = a2; g[s][jj * 4 + 3] = a3;
            sum   += a0 + a1 + a2 + a3;
            sumsq += a0 * a0 + a1 * a1 + a2 * a2 + a3 * a3;
        }
#pragma unroll
        for (int off = 32; off; off >>= 1) {
            sum   += __shfl_xor(sum, off, 64);
            sumsq += __shfl_xor(sumsq, off, 64);
        }
        float m = sum * (1.0f / 1024.0f);
        float var = sumsq * (1.0f / 1024.0f) - m * m;
        mu[s] = m;
        rs[s] = rsqrtf(var + 1e-5f);
    }

    const float* gm0 = gamma + (size_t)e0 * D_OUT;
    const float* bt0 = beta  + (size_t)e0 * D_OUT;
    const float* gm1 = gamma + (size_t)e1 * D_OUT;
    const float* bt1 = beta  + (size_t)e1 * D_OUT;
    float* orow = out + (size_t)token * D_OUT;
#pragma unroll
    for (int jj = 0; jj < 4; ++jj) {
        int n = jj * 256 + lane * 4;
        float4 gmA = *(const float4*)(gm0 + n);
        float4 btA = *(const float4*)(bt0 + n);
        float4 gmB = *(const float4*)(gm1 + n);
        float4 btB = *(const float4*)(bt1 + n);
        float4 o;
        o.x = gate0 * ((g[0][jj * 4 + 0] - mu[0]) * rs[0] * gmA.x + btA.x)
            + gate1 * ((g[1][jj * 4 + 0] - mu[1]) * rs[1] * gmB.x + btB.x);
        o.y = gate0 * ((g[0][jj * 4 + 1] - mu[0]) * rs[0] * gmA.y + btA.y)
            + gate1 * ((g[1][jj * 4 + 1] - mu[1]) * rs[1] * gmB.y + btB.y);
        o.z = gate0 * ((g[0][jj * 4 + 2] - mu[0]) * rs[0] * gmA.z + btA.z)
            + gate1 * ((g[1][jj * 4 + 2] - mu[1]) * rs[1] * gmB.z + btB.z);
        o.w = gate0 * ((g[0][jj * 4 + 3] - mu[0]) * rs[0] * gmA.w + btA.w)
            + gate1 * ((g[1][jj * 4 + 3] - mu[1]) * rs[1] * gmB.w + btB.w);
        *(float4*)(orow + n) = o;
    }
}

extern "C" void kernel_launch(void* const* d_in, const int* in_sizes, int n_in,
                              void* d_out, int out_size, void* d_ws, size_t ws_size,
                              hipStream_t stream) {
    const float* x     = (const float*)d_in[0];
    const float* Wg    = (const float*)d_in[1];
    const float* bg    = (const float*)d_in[2];
    const float* We    = (const float*)d_in[3];
    const float* be    = (const float*)d_in[4];
    const float* gamma = (const float*)d_in[5];
    const float* beta  = (const float*)d_in[6];
    float* out = (float*)d_out;

    char* w = (char*)d_ws;
    size_t off = 0;
    int*   cnt   = (int*)(w + off);            off += (size_t)16 * CNT_STRIDE * 4;
    int*   top_i = (int*)(w + off);            off += (size_t)N_TOK * 2 * 4;
    float* gates = (float*)(w + off);          off += (size_t)N_TOK * 2 * 4;
    int*   lists = (int*)(w + off);            off += (size_t)16 * N_TOK * 4;
    unsigned short* WeT = (unsigned short*)(w + off); off += (size_t)NE * D_IN * D_OUT * 2;
    unsigned short* h   = (unsigned short*)(w + off); off += (size_t)N_TOK * D_OUT * 2;
    size_t xb_bytes = (size_t)N_TOK * D_IN * 2;
    bool use_bf = (off + xb_bytes) <= ws_size;
    unsigned short* xb = use_bf ? (unsigned short*)(w + off) : h;
    if (use_bf) off += xb_bytes;
    size_t h1_bytes = (size_t)N_TOK * D_OUT * 2;
    bool use_fused = use_bf && (off + h1_bytes) <= ws_size;
    unsigned short* h1 = use_fused ? (unsigned short*)(w + off) : h;
    if (use_fused) off += h1_bytes;

    zero_cnt<<<(16 * CNT_STRIDE + 255) / 256, 256, 0, stream>>>(cnt);
    transpose_we<<<dim3(16, 16, NE), 256, 0, stream>>>(We, WeT);
    gate_kernel<<<N_TOK / GBLK, 256, 0, stream>>>(x, Wg, bg, top_i, gates, cnt, lists, xb);

    if (use_fused) {
        gemm_slot2<<<dim3(D_OUT / BN, N_TOK / BM, 16), 256, 0, stream>>>(
            xb, WeT, be, lists, cnt, 0, h, h1);
        ln_combine2<<<N_TOK / 4, 256, 0, stream>>>(h, h1, gamma, beta, gates, top_i, out);
    } else if (use_bf) {
        for (int s = 0; s < 2; ++s) {
            gemm_slot2<<<dim3(D_OUT / BN, N_TOK / BM, 8), 256, 0, stream>>>(
                xb, WeT, be, lists, cnt, s * 8, h, h);
            ln_combine<<<N_TOK / 4, 256, 0, stream>>>(h, gamma, beta, gates, top_i, s, out);
        }
    } else {
        for (int s = 0; s < 2; ++s) {
            gemm_slot_f32<<<dim3(D_OUT / BN, N_TOK / BM, 8), 256, 0, stream>>>(
                x, WeT, be, lists, cnt, s, h);
            ln_combine<<<N_TOK / 4, 256, 0, stream>>>(h, gamma, beta, gates, top_i, s, out);
        }
    }
}

// Round 3
// 555.108 us; speedup vs baseline: 1.4746x; 1.0502x over previous
//
#include <hip/hip_runtime.h>
#include <hip/hip_bf16.h>

#define N_TOK 32768
#define D_IN 1024
#define D_OUT 1024
#define NE 8

#define BM 128
#define BN 128
#define BK 64
#define PAD 72  // (legacy fallback path only)

#define GBLK 64        // tokens per gate block (64 rows, 4 lanes per token)
#define GCH 64         // dims per staged chunk
#define NCH (D_IN / GCH)
#define CNT_STRIDE 64  // ints; pads each routing counter to its own 256B cache line

#define AS1 __attribute__((address_space(1)))
#define AS3 __attribute__((address_space(3)))

typedef __attribute__((ext_vector_type(8))) short short8;
typedef __attribute__((ext_vector_type(4))) float floatx4;

__device__ __forceinline__ unsigned short f2bf(float f) {
    union { float f; unsigned u; } v; v.f = f;
    unsigned r = v.u + 0x7fffu + ((v.u >> 16) & 1u);  // RNE
    return (unsigned short)(r >> 16);
}
__device__ __forceinline__ float bf2f(unsigned short u) {
    union { unsigned u; float f; } v; v.u = ((unsigned)u) << 16;
    return v.f;
}

// async 16B global->LDS (direct, no VGPR round trip). Global addr is per-lane;
// LDS dest must be wave-uniform base (+ lane*16 implicit).
__device__ __forceinline__ void gl_lds16(const void* g, void* l) {
    __builtin_amdgcn_global_load_lds((const AS1 unsigned int*)g,
                                     (AS3 unsigned int*)l, 16, 0, 0);
}

// ---------------- zero the padded routing counters ----------------------------
__global__ void zero_cnt(int* __restrict__ cnt) {
    int i = blockIdx.x * 256 + threadIdx.x;
    if (i < 16 * CNT_STRIDE) cnt[i] = 0;
}

// ---------------- We [e][i][o] fp32 -> WeT [e][o][i] bf16 ---------------------
__global__ __launch_bounds__(256) void transpose_we(
    const float* __restrict__ We, unsigned short* __restrict__ WeT)
{
    __shared__ unsigned short tile[64 * 65];
    int e = blockIdx.z;
    int i0 = blockIdx.x * 64, o0 = blockIdx.y * 64;
    const float* src = We + ((size_t)e * D_IN + i0) * D_OUT + o0;
#pragma unroll
    for (int it = 0; it < 16; ++it) {
        int idx = threadIdx.x + it * 256;      // 0..4095
        int r = idx >> 6, c = idx & 63;
        tile[r * 65 + c] = f2bf(src[(size_t)r * D_OUT + c]);
    }
    __syncthreads();
    unsigned short* dst = WeT + ((size_t)e * D_OUT + o0) * D_IN + i0;
#pragma unroll
    for (int it = 0; it < 16; ++it) {
        int idx = threadIdx.x + it * 256;
        int r = idx >> 6, c = idx & 63;
        dst[(size_t)r * D_IN + c] = tile[c * 65 + r];
    }
}

// ---------------- gating v2: 4 lanes/token, chunked LDS staging ---------------
__global__ __launch_bounds__(256) void gate_kernel(
    const float* __restrict__ x, const float* __restrict__ Wg,
    const float* __restrict__ bg,
    int* __restrict__ top_i, float* __restrict__ gates,
    int* __restrict__ cnt, int* __restrict__ lists,
    unsigned short* __restrict__ xb)
{
    __shared__ float xs[GBLK][GCH + 1];   // pitch 65: compute reads 2-way (free)
    __shared__ float wgs[4][136];         // q-pitch 136: b128 starts 8 banks apart
    __shared__ int lcnt[16];
    __shared__ int lbase[16];
    __shared__ int ltoks[16][GBLK];

    int tid = threadIdx.x;
    if (tid < 16) lcnt[tid] = 0;

    int tok0 = blockIdx.x * GBLK;
    int lane = tid & 63, wave = tid >> 6;
    int t = lane >> 2, q = lane & 3;
    int row = wave * 16 + t;              // block-local token owned by this lane
    int token = tok0 + row;

    double acc[NE] = {};

#pragma unroll 1
    for (int c = 0; c < NCH; ++c) {
        int cb = c * GCH;
        __syncthreads();                  // previous chunk fully consumed
        {
            int i = tid;
#pragma unroll
            for (int it = 0; it < 2; ++it, i += 256) {
                float v = Wg[(size_t)cb * NE + i];
                int d = i >> 3, e = i & 7;            // d in [0,64)
                wgs[d >> 4][(d & 15) * 8 + e] = v;
            }
        }
#pragma unroll
        for (int it = 0; it < 4; ++it) {
            int idx = tid + it * 256;                 // 0..1023 float4 slots
            int r = idx >> 4, c4 = (idx & 15) * 4;
            const float4 v = *(const float4*)(x + (size_t)(tok0 + r) * D_IN + cb + c4);
            xs[r][c4 + 0] = v.x; xs[r][c4 + 1] = v.y;
            xs[r][c4 + 2] = v.z; xs[r][c4 + 3] = v.w;
            ushort4 pk;
            pk.x = f2bf(v.x); pk.y = f2bf(v.y); pk.z = f2bf(v.z); pk.w = f2bf(v.w);
            *(ushort4*)(xb + (size_t)(tok0 + r) * D_IN + cb + c4) = pk;
        }
        __syncthreads();
#pragma unroll
        for (int jj = 0; jj < 16; ++jj) {
            double xd = (double)xs[row][q * 16 + jj];
            const float* wr = &wgs[q][jj * 8];
#pragma unroll
            for (int e = 0; e < NE; ++e)
                acc[e] += xd * (double)wr[e];
        }
    }

#pragma unroll
    for (int off = 1; off <= 2; off <<= 1)
#pragma unroll
        for (int e = 0; e < NE; ++e)
            acc[e] += __shfl_xor(acc[e], off, 64);

    float lg[NE];
#pragma unroll
    for (int e = 0; e < NE; ++e) lg[e] = tanhf((float)(acc[e] + (double)bg[e]));
    int i0 = 0;
    for (int e = 1; e < NE; ++e) if (lg[e] > lg[i0]) i0 = e;   // lowest idx wins ties
    int i1 = (i0 == 0) ? 1 : 0;
    for (int e = 0; e < NE; ++e) { if (e == i0) continue; if (lg[e] > lg[i1]) i1 = e; }
    float tt = expf(lg[i1] - lg[i0]);
    float g0 = 1.0f / (1.0f + tt);
    float g1 = tt * g0;

    if (q == 0) {
        top_i[token * 2 + 0] = i0; top_i[token * 2 + 1] = i1;
        gates[token * 2 + 0] = g0; gates[token * 2 + 1] = g1;
        int p0 = atomicAdd(&lcnt[i0], 1);
        ltoks[i0][p0] = token;
        int p1 = atomicAdd(&lcnt[NE + i1], 1);
        ltoks[NE + i1][p1] = token;
    }
    __syncthreads();
    if (tid < 16) lbase[tid] = atomicAdd(&cnt[tid * CNT_STRIDE], lcnt[tid]);
    __syncthreads();
    int g = tid >> 4, j = tid & 15;
    int n = lcnt[g];
    int* dst = lists + (size_t)g * N_TOK + lbase[g];
    for (int k = j; k < n; k += 16) dst[k] = ltoks[g][k];
}

// ---------------- gathered-token bf16 MFMA GEMM v3 ----------------------------
// global_load_lds(16B) direct staging, linear LDS, both-sides XOR swizzle, and
// load-balanced XCD-local work remap: hw block o = bx + 8*by -> XCD = o&7.
// Each XCD takes a contiguous ntile-fastest slab of the ACTIVE work (mact
// known only in-kernel), so the 8 blocks sharing an A-tile are XCD-local ->
// A fetched ~once instead of 8x. Perf-only remap; correctness mapping-free.
__global__ __launch_bounds__(256) void gemm_slot2(
    const unsigned short* __restrict__ xb,
    const unsigned short* __restrict__ WeT,
    const float* __restrict__ be, const int* __restrict__ lists,
    const int* __restrict__ cnt, int zoff,
    unsigned short* __restrict__ h0, unsigned short* __restrict__ h1)
{
    int z = blockIdx.z + zoff;
    int slot = z >> 3, e = z & 7;
    unsigned short* __restrict__ h = slot ? h1 : h0;
    int count = cnt[z * CNT_STRIDE];
    int mact = (count + BM - 1) >> 7;          // active mtiles
    int o = blockIdx.x + 8 * blockIdx.y;       // hw linear within z (x fastest)
    int xcd = o & 7, idx = o >> 3;
    if (idx >= mact) return;                   // each XCD handles exactly mact items
    int wk = xcd * mact + idx;                 // bijection onto [0, 8*mact)
    int m0 = (wk >> 3) * BM;                   // ntile-fastest within the slab
    int n0 = (wk & 7) * BN;
    const int* list = lists + (size_t)z * N_TOK;

    __shared__ int toks[BM];
    __shared__ __align__(16) unsigned short As[BM * BK];   // 16 KB, linear+swizzled
    __shared__ __align__(16) unsigned short Bs[BN * BK];   // 16 KB

    int tid = threadIdx.x;
    if (tid < BM) {
        int r = m0 + tid; if (r > count - 1) r = count - 1;  // tail duplicates last row
        toks[tid] = list[r];
    }
    __syncthreads();

    int lane = tid & 63, wave = tid >> 6;
    int wm = (wave & 1) * 64, wn = (wave >> 1) * 64;
    int q = lane & 15, quad = lane >> 4;

    const unsigned short* Bglob = WeT + ((size_t)e * D_OUT + n0) * D_IN;

    // Precompute per-thread staging addresses (source pre-swizzled chunk).
    const unsigned short* asrc[4];
    const unsigned short* bsrc[4];
    unsigned short* adst[4];
    unsigned short* bdst[4];
#pragma unroll
    for (int it = 0; it < 4; ++it) {
        int idx2 = tid + it * 256;           // 0..1023 16B-chunks
        int m = idx2 >> 3, c = idx2 & 7;
        int sc = c ^ (m & 7);                // inverse(=same) of read-side XOR
        asrc[it] = xb + (size_t)toks[m] * D_IN + sc * 8;
        bsrc[it] = Bglob + (size_t)m * D_IN + sc * 8;
        adst[it] = As + (size_t)(it * 256 + (tid & 192)) * 8;  // wave-uniform
        bdst[it] = Bs + (size_t)(it * 256 + (tid & 192)) * 8;
    }

    floatx4 acc[4][4] = {};

    for (int kb = 0; kb < D_IN; kb += BK) {
#pragma unroll
        for (int it = 0; it < 4; ++it)
            gl_lds16(asrc[it] + kb, adst[it]);
#pragma unroll
        for (int it = 0; it < 4; ++it)
            gl_lds16(bsrc[it] + kb, bdst[it]);
        __syncthreads();                      // drains vmcnt before use

#pragma unroll
        for (int ks = 0; ks < BK; ks += 32) {
            int cb = ks >> 3;                 // chunk base: 0 or 4
            short8 af[4], bfr[4];
#pragma unroll
            for (int i = 0; i < 4; ++i) {
                int row = wm + i * 16 + q;
                int ch = (cb + quad) ^ (row & 7);
                af[i] = *(const short8*)&As[row * BK + ch * 8];
            }
#pragma unroll
            for (int j = 0; j < 4; ++j) {
                int row = wn + j * 16 + q;
                int ch = (cb + quad) ^ (row & 7);
                bfr[j] = *(const short8*)&Bs[row * BK + ch * 8];
            }
#pragma unroll
            for (int i = 0; i < 4; ++i)
#pragma unroll
                for (int j = 0; j < 4; ++j)
                    acc[i][j] = __builtin_amdgcn_mfma_f32_16x16x32_bf16(
                        af[i], bfr[j], acc[i][j], 0, 0, 0);
        }
        __syncthreads();
    }

#pragma unroll
    for (int i = 0; i < 4; ++i) {
#pragma unroll
        for (int r = 0; r < 4; ++r) {
            int m = wm + i * 16 + quad * 4 + r;
            if (m0 + m < count) {
                int tok = toks[m];
#pragma unroll
                for (int j = 0; j < 4; ++j) {
                    int n = n0 + wn + j * 16 + q;
                    float v = acc[i][j][r] + be[(size_t)e * D_OUT + n];
                    h[(size_t)tok * D_OUT + n] = f2bf(v);
                }
            }
        }
    }
}

// ---------------- legacy reg-staged GEMM (fallback when xb doesn't fit) ------
__global__ __launch_bounds__(256) void gemm_slot_f32(
    const float* __restrict__ x,
    const unsigned short* __restrict__ WeT,
    const float* __restrict__ be, const int* __restrict__ lists,
    const int* __restrict__ cnt, int slot, unsigned short* __restrict__ h)
{
    int e = blockIdx.z;
    int count = cnt[(slot * NE + e) * CNT_STRIDE];
    int m0 = blockIdx.y * BM;
    if (m0 >= count) return;
    int n0 = blockIdx.x * BN;
    const int* list = lists + (size_t)(slot * NE + e) * N_TOK;

    __shared__ int toks[BM];
    __shared__ unsigned short As[BM * PAD];
    __shared__ unsigned short Bs[BN * PAD];

    int tid = threadIdx.x;
    if (tid < BM) {
        int r = m0 + tid; if (r > count - 1) r = count - 1;
        toks[tid] = list[r];
    }
    __syncthreads();

    int lane = tid & 63, wave = tid >> 6;
    int wm = (wave & 1) * 64, wn = (wave >> 1) * 64;
    int q = lane & 15, quad = lane >> 4;

    floatx4 acc[4][4] = {};
    const unsigned short* Bglob = WeT + ((size_t)e * D_OUT + n0) * D_IN;

    for (int kb = 0; kb < D_IN; kb += BK) {
#pragma unroll
        for (int it = 0; it < 8; ++it) {
            int idx = tid + it * 256;
            int m = idx >> 4, kq = idx & 15;
            float4 v = *(const float4*)(x + (size_t)toks[m] * D_IN + kb + kq * 4);
            ushort4 pk;
            pk.x = f2bf(v.x); pk.y = f2bf(v.y); pk.z = f2bf(v.z); pk.w = f2bf(v.w);
            *(ushort4*)&As[m * PAD + kq * 4] = pk;
        }
#pragma unroll
        for (int it = 0; it < 4; ++it) {
            int idx = tid + it * 256;
            int n = idx >> 3, kq = idx & 7;
            *(uint4*)&Bs[n * PAD + kq * 8] =
                *(const uint4*)(Bglob + (size_t)n * D_IN + kb + kq * 8);
        }
        __syncthreads();
#pragma unroll
        for (int ks = 0; ks < BK; ks += 32) {
            short8 af[4], bfr[4];
#pragma unroll
            for (int i = 0; i < 4; ++i)
                af[i] = *(const short8*)&As[(wm + i * 16 + q) * PAD + ks + quad * 8];
#pragma unroll
            for (int j = 0; j < 4; ++j)
                bfr[j] = *(const short8*)&Bs[(wn + j * 16 + q) * PAD + ks + quad * 8];
#pragma unroll
            for (int i = 0; i < 4; ++i)
#pragma unroll
                for (int j = 0; j < 4; ++j)
                    acc[i][j] = __builtin_amdgcn_mfma_f32_16x16x32_bf16(
                        af[i], bfr[j], acc[i][j], 0, 0, 0);
        }
        __syncthreads();
    }

#pragma unroll
    for (int i = 0; i < 4; ++i) {
#pragma unroll
        for (int r = 0; r < 4; ++r) {
            int m = wm + i * 16 + quad * 4 + r;
            if (m0 + m < count) {
                int tok = toks[m];
#pragma unroll
                for (int j = 0; j < 4; ++j) {
                    int n = n0 + wn + j * 16 + q;
                    float v = acc[i][j][r] + be[(size_t)e * D_OUT + n];
                    h[(size_t)tok * D_OUT + n] = f2bf(v);
                }
            }
        }
    }
}

// ---------------- GELU(exact) + LN + affine, one slot (fallback) --------------
__global__ __launch_bounds__(256) void ln_combine(
    const unsigned short* __restrict__ h, const float* __restrict__ gamma,
    const float* __restrict__ beta, const float* __restrict__ gates,
    const int* __restrict__ top_i, int slot, float* __restrict__ out)
{
    int wave = threadIdx.x >> 6, lane = threadIdx.x & 63;
    int token = blockIdx.x * 4 + wave;
    int e = top_i[token * 2 + slot];
    float gate = gates[token * 2 + slot];
    const unsigned short* hr = h + (size_t)token * D_OUT;

    float g[16], sum = 0.f, sumsq = 0.f;
#pragma unroll
    for (int jj = 0; jj < 4; ++jj) {
        int n = jj * 256 + lane * 4;
        uint2 pk = *(const uint2*)(hr + n);
        float v0 = bf2f((unsigned short)(pk.x & 0xffff));
        float v1 = bf2f((unsigned short)(pk.x >> 16));
        float v2 = bf2f((unsigned short)(pk.y & 0xffff));
        float v3 = bf2f((unsigned short)(pk.y >> 16));
        float g0 = 0.5f * v0 * (1.0f + erff(v0 * 0.70710678118654752f));
        float g1 = 0.5f * v1 * (1.0f + erff(v1 * 0.70710678118654752f));
        float g2 = 0.5f * v2 * (1.0f + erff(v2 * 0.70710678118654752f));
        float g3 = 0.5f * v3 * (1.0f + erff(v3 * 0.70710678118654752f));
        g[jj * 4 + 0] = g0; g[jj * 4 + 1] = g1; g[jj * 4 + 2] = g2; g[jj * 4 + 3] = g3;
        sum   += g0 + g1 + g2 + g3;
        sumsq += g0 * g0 + g1 * g1 + g2 * g2 + g3 * g3;
    }
#pragma unroll
    for (int off = 32; off; off >>= 1) {
        sum   += __shfl_xor(sum, off, 64);
        sumsq += __shfl_xor(sumsq, off, 64);
    }
    float mu  = sum * (1.0f / 1024.0f);
    float var = sumsq * (1.0f / 1024.0f) - mu * mu;
    float rs  = rsqrtf(var + 1e-5f);

    const float* gm = gamma + (size_t)e * D_OUT;
    const float* bt = beta  + (size_t)e * D_OUT;
    float* orow = out + (size_t)token * D_OUT;
#pragma unroll
    for (int jj = 0; jj < 4; ++jj) {
        int n = jj * 256 + lane * 4;
        float4 gm4 = *(const float4*)(gm + n);
        float4 bt4 = *(const float4*)(bt + n);
        float4 o;
        o.x = gate * ((g[jj * 4 + 0] - mu) * rs * gm4.x + bt4.x);
        o.y = gate * ((g[jj * 4 + 1] - mu) * rs * gm4.y + bt4.y);
        o.z = gate * ((g[jj * 4 + 2] - mu) * rs * gm4.z + bt4.z);
        o.w = gate * ((g[jj * 4 + 3] - mu) * rs * gm4.w + bt4.w);
        if (slot == 0) {
            *(float4*)(orow + n) = o;
        } else {
            float4 p = *(const float4*)(orow + n);
            p.x += o.x; p.y += o.y; p.z += o.z; p.w += o.w;
            *(float4*)(orow + n) = p;
        }
    }
}

// ---------------- fused both-slot GELU + LN + gated combine -------------------
__global__ __launch_bounds__(256) void ln_combine2(
    const unsigned short* __restrict__ h0, const unsigned short* __restrict__ h1,
    const float* __restrict__ gamma, const float* __restrict__ beta,
    const float* __restrict__ gates, const int* __restrict__ top_i,
    float* __restrict__ out)
{
    int wave = threadIdx.x >> 6, lane = threadIdx.x & 63;
    int token = blockIdx.x * 4 + wave;
    int e0 = top_i[token * 2 + 0], e1 = top_i[token * 2 + 1];
    float gate0 = gates[token * 2 + 0], gate1 = gates[token * 2 + 1];

    float g[2][16], mu[2], rs[2];
    const unsigned short* hr[2] = { h0 + (size_t)token * D_OUT,
                                    h1 + (size_t)token * D_OUT };
#pragma unroll
    for (int s = 0; s < 2; ++s) {
        float sum = 0.f, sumsq = 0.f;
#pragma unroll
        for (int jj = 0; jj < 4; ++jj) {
            int n = jj * 256 + lane * 4;
            uint2 pk = *(const uint2*)(hr[s] + n);
            float v0 = bf2f((unsigned short)(pk.x & 0xffff));
            float v1 = bf2f((unsigned short)(pk.x >> 16));
            float v2 = bf2f((unsigned short)(pk.y & 0xffff));
            float v3 = bf2f((unsigned short)(pk.y >> 16));
            float a0 = 0.5f * v0 * (1.0f + erff(v0 * 0.70710678118654752f));
            float a1 = 0.5f * v1 * (1.0f + erff(v1 * 0.70710678118654752f));
            float a2 = 0.5f * v2 * (1.0f + erff(v2 * 0.70710678118654752f));
            float a3 = 0.5f * v3 * (1.0f + erff(v3 * 0.70710678118654752f));
            g[s][jj * 4 + 0] = a0; g[s][jj * 4 + 1] = a1;
            g[s][jj * 4 + 2] = a2; g[s][jj * 4 + 3] = a3;
            sum   += a0 + a1 + a2 + a3;
            sumsq += a0 * a0 + a1 * a1 + a2 * a2 + a3 * a3;
        }
#pragma unroll
        for (int off = 32; off; off >>= 1) {
            sum   += __shfl_xor(sum, off, 64);
            sumsq += __shfl_xor(sumsq, off, 64);
        }
        float m = sum * (1.0f / 1024.0f);
        float var = sumsq * (1.0f / 1024.0f) - m * m;
        mu[s] = m;
        rs[s] = rsqrtf(var + 1e-5f);
    }

    const float* gm0 = gamma + (size_t)e0 * D_OUT;
    const float* bt0 = beta  + (size_t)e0 * D_OUT;
    const float* gm1 = gamma + (size_t)e1 * D_OUT;
    const float* bt1 = beta  + (size_t)e1 * D_OUT;
    float* orow = out + (size_t)token * D_OUT;
#pragma unroll
    for (int jj = 0; jj < 4; ++jj) {
        int n = jj * 256 + lane * 4;
        float4 gmA = *(const float4*)(gm0 + n);
        float4 btA = *(const float4*)(bt0 + n);
        float4 gmB = *(const float4*)(gm1 + n);
        float4 btB = *(const float4*)(bt1 + n);
        float4 o;
        o.x = gate0 * ((g[0][jj * 4 + 0] - mu[0]) * rs[0] * gmA.x + btA.x)
            + gate1 * ((g[1][jj * 4 + 0] - mu[1]) * rs[1] * gmB.x + btB.x);
        o.y = gate0 * ((g[0][jj * 4 + 1] - mu[0]) * rs[0] * gmA.y + btA.y)
            + gate1 * ((g[1][jj * 4 + 1] - mu[1]) * rs[1] * gmB.y + btB.y);
        o.z = gate0 * ((g[0][jj * 4 + 2] - mu[0]) * rs[0] * gmA.z + btA.z)
            + gate1 * ((g[1][jj * 4 + 2] - mu[1]) * rs[1] * gmB.z + btB.z);
        o.w = gate0 * ((g[0][jj * 4 + 3] - mu[0]) * rs[0] * gmA.w + btA.w)
            + gate1 * ((g[1][jj * 4 + 3] - mu[1]) * rs[1] * gmB.w + btB.w);
        *(float4*)(orow + n) = o;
    }
}

extern "C" void kernel_launch(void* const* d_in, const int* in_sizes, int n_in,
                              void* d_out, int out_size, void* d_ws, size_t ws_size,
                              hipStream_t stream) {
    const float* x     = (const float*)d_in[0];
    const float* Wg    = (const float*)d_in[1];
    const float* bg    = (const float*)d_in[2];
    const float* We    = (const float*)d_in[3];
    const float* be    = (const float*)d_in[4];
    const float* gamma = (const float*)d_in[5];
    const float* beta  = (const float*)d_in[6];
    float* out = (float*)d_out;

    char* w = (char*)d_ws;
    size_t off = 0;
    int*   cnt   = (int*)(w + off);            off += (size_t)16 * CNT_STRIDE * 4;
    int*   top_i = (int*)(w + off);            off += (size_t)N_TOK * 2 * 4;
    float* gates = (float*)(w + off);          off += (size_t)N_TOK * 2 * 4;
    int*   lists = (int*)(w + off);            off += (size_t)16 * N_TOK * 4;
    unsigned short* WeT = (unsigned short*)(w + off); off += (size_t)NE * D_IN * D_OUT * 2;
    unsigned short* h   = (unsigned short*)(w + off); off += (size_t)N_TOK * D_OUT * 2;
    size_t xb_bytes = (size_t)N_TOK * D_IN * 2;
    bool use_bf = (off + xb_bytes) <= ws_size;
    unsigned short* xb = use_bf ? (unsigned short*)(w + off) : h;
    if (use_bf) off += xb_bytes;
    size_t h1_bytes = (size_t)N_TOK * D_OUT * 2;
    bool use_fused = use_bf && (off + h1_bytes) <= ws_size;
    unsigned short* h1 = use_fused ? (unsigned short*)(w + off) : h;
    if (use_fused) off += h1_bytes;

    zero_cnt<<<(16 * CNT_STRIDE + 255) / 256, 256, 0, stream>>>(cnt);
    transpose_we<<<dim3(16, 16, NE), 256, 0, stream>>>(We, WeT);
    gate_kernel<<<N_TOK / GBLK, 256, 0, stream>>>(x, Wg, bg, top_i, gates, cnt, lists, xb);

    if (use_fused) {
        gemm_slot2<<<dim3(D_OUT / BN, N_TOK / BM, 16), 256, 0, stream>>>(
            xb, WeT, be, lists, cnt, 0, h, h1);
        ln_combine2<<<N_TOK / 4, 256, 0, stream>>>(h, h1, gamma, beta, gates, top_i, out);
    } else if (use_bf) {
        for (int s = 0; s < 2; ++s) {
            gemm_slot2<<<dim3(D_OUT / BN, N_TOK / BM, 8), 256, 0, stream>>>(
                xb, WeT, be, lists, cnt, s * 8, h, h);
            ln_combine<<<N_TOK / 4, 256, 0, stream>>>(h, gamma, beta, gates, top_i, s, out);
        }
    } else {
        for (int s = 0; s < 2; ++s) {
            gemm_slot_f32<<<dim3(D_OUT / BN, N_TOK / BM, 8), 256, 0, stream>>>(
                x, WeT, be, lists, cnt, s, h);
            ln_combine<<<N_TOK / 4, 256, 0, stream>>>(h, gamma, beta, gates, top_i, s, out);
        }
    }
}